// Round 5
// baseline (1476.228 us; speedup 1.0000x reference)
//
#include <hip/hip_runtime.h>
#include <stdint.h>

#define NE   1024
#define ED   256
#define NB   2
#define S    32768            // 32*32*32
#define TOKENS (NB*S)         // 65536

#define OFF_LOSS 16777216
#define OFF_IDX  16777217
#define OFF_SAMP 16842753
#define OFF_MD   16844801
#define OFF_MV   16844802

#define TAU 8e-4f             // fp16-filter ambiguity margin (safe bound ~2.9e-4)

typedef _Float16 half8 __attribute__((ext_vector_type(8)));
typedef float floatx4 __attribute__((ext_vector_type(4)));

// ---------------- codebook norms: bitwise numpy pairwise sum ----------------
__global__ void k_enorm(const float* __restrict__ emb, float* __restrict__ en) {
#pragma clang fp contract(off)
  int j = blockIdx.x * 256 + threadIdx.x;
  const float* e = emb + (size_t)j * ED;
  float halves[2];
  for (int h = 0; h < 2; ++h) {
    const float* a = e + h * 128;
    float r[8];
    for (int k = 0; k < 8; ++k) r[k] = a[k] * a[k];
    for (int i = 8; i < 128; i += 8)
      for (int k = 0; k < 8; ++k) r[k] += a[i + k] * a[i + k];
    halves[h] = ((r[0] + r[1]) + (r[2] + r[3])) + ((r[4] + r[5]) + (r[6] + r[7]));
  }
  en[j] = halves[0] + halves[1];
}

// ---------------- emb -> fragment-ordered fp16 ----------------
// B-frag for (ntile, kstep): lane holds e[nt*16 + (lane&15)][ks*32 + (lane>>4)*8 + j]
// stored contiguously at ((nt*8+ks)*64 + lane)*8 halves.
__global__ void k_cvt(const float* __restrict__ emb, _Float16* __restrict__ embf) {
  int g = blockIdx.x * 512 + threadIdx.x;   // 64 blocks x 512 = 32768
  int lane = g & 63;
  int ks = (g >> 6) & 7;
  int nt = g >> 9;
  int n = nt * 16 + (lane & 15);
  int k0 = ks * 32 + (lane >> 4) * 8;
  const float* src = emb + (size_t)n * ED + k0;
  half8 v;
#pragma unroll
  for (int j = 0; j < 8; ++j) v[j] = (_Float16)src[j];
  *(half8*)(embf + ((size_t)((nt * 8 + ks) * 64 + lane)) * 8) = v;
}

// ---------------- MFMA filter: approx argmin + top-2 ambiguity ----------------
// 128 tokens/block, 256 thr = 4 waves; wave w owns tokens [w*32, w*32+32)
// (2 m-stripes of 16). Sweeps all 1024 codes via 64 n-tiles of 16x16x32 mfma.
__global__ void __launch_bounds__(256)
k_filter(const float* __restrict__ z, const _Float16* __restrict__ embf,
         const float* __restrict__ en, float* __restrict__ out_idx,
         int* __restrict__ amb_cnt, int* __restrict__ amb_list) {
  __shared__ _Float16 zA[128 * 264];   // [tok][c], stride 264 -> 2-way banks
  __shared__ float en_s[NE];

  int tid = threadIdx.x;
  int lane = tid & 63;
  int w = tid >> 6;
  int mrow = lane & 15;
  int quad = lane >> 4;
  int t0 = blockIdx.x * 128;
  int b = t0 >> 15;                    // 32768 % 128 == 0: no straddle
  int s0 = t0 & 32767;

  for (int i = tid; i < NE; i += 256) en_s[i] = en[i];

  {  // stage z tile -> fp16 LDS (coalesced along s, rne convert)
    int tok = tid & 127;
    int ch = tid >> 7;
    const float* zb = z + (size_t)b * ED * S + s0 + tok;
    for (int it = 0; it < 16; ++it) {
      int c0 = ch * 8 + it * 16;
      half8 v;
#pragma unroll
      for (int j = 0; j < 8; ++j) v[j] = (_Float16)zb[(size_t)(c0 + j) * S];
      *(half8*)(&zA[tok * 264 + c0]) = v;
    }
  }
  __syncthreads();

  // A-frags register-resident: af[stripe][kstep]
  half8 af[2][8];
#pragma unroll
  for (int s = 0; s < 2; ++s)
#pragma unroll
    for (int ks = 0; ks < 8; ++ks)
      af[s][ks] = *(const half8*)(&zA[(w * 32 + s * 16 + mrow) * 264 + ks * 32 + quad * 8]);

  float m1[2][4], m2[2][4];
  int j1[2][4];
#pragma unroll
  for (int s = 0; s < 2; ++s)
#pragma unroll
    for (int r = 0; r < 4; ++r) { m1[s][r] = 3.4e38f; m2[s][r] = 3.4e38f; j1[s][r] = 0; }

  for (int nt = 0; nt < 64; ++nt) {
    floatx4 acc0 = {0.f, 0.f, 0.f, 0.f}, acc1 = {0.f, 0.f, 0.f, 0.f};
    const half8* pb = (const half8*)(embf + ((size_t)(nt * 8) * 64 + lane) * 8);
#pragma unroll
    for (int ks = 0; ks < 8; ++ks) {
      half8 bf = pb[ks * 64];          // coalesced 16B/lane from L2
      acc0 = __builtin_amdgcn_mfma_f32_16x16x32_f16(af[0][ks], bf, acc0, 0, 0, 0);
      acc1 = __builtin_amdgcn_mfma_f32_16x16x32_f16(af[1][ks], bf, acc1, 0, 0, 0);
    }
    int j = nt * 16 + mrow;
    float Bj = en_s[j];                // ||z||^2 constant per token -> dropped
#pragma unroll
    for (int r = 0; r < 4; ++r) {
      float d0 = Bj - 2.f * acc0[r];
      float d1 = Bj - 2.f * acc1[r];
      if (d0 < m1[0][r]) { m2[0][r] = m1[0][r]; m1[0][r] = d0; j1[0][r] = j; }
      else if (d0 < m2[0][r]) m2[0][r] = d0;
      if (d1 < m1[1][r]) { m2[1][r] = m1[1][r]; m1[1][r] = d1; j1[1][r] = j; }
      else if (d1 < m2[1][r]) m2[1][r] = d1;
    }
  }

  // merge across the 16 lanes of each quad (they share tokens, differ in codes)
#pragma unroll
  for (int d = 1; d < 16; d <<= 1) {
#pragma unroll
    for (int s = 0; s < 2; ++s)
#pragma unroll
      for (int r = 0; r < 4; ++r) {
        float om1 = __shfl_xor(m1[s][r], d, 64);
        float om2 = __shfl_xor(m2[s][r], d, 64);
        int oj = __shfl_xor(j1[s][r], d, 64);
        float hi;
        if (om1 < m1[s][r] || (om1 == m1[s][r] && oj < j1[s][r])) {
          hi = m1[s][r]; m1[s][r] = om1; j1[s][r] = oj;
        } else hi = om1;                 // equal-m1 merges force m2==m1 -> flagged
        m2[s][r] = fminf(m2[s][r], fminf(om2, hi));
      }
  }

  if (mrow == 0) {
#pragma unroll
    for (int s = 0; s < 2; ++s)
#pragma unroll
      for (int r = 0; r < 4; ++r) {
        int tok = w * 32 + s * 16 + quad * 4 + r;
        out_idx[t0 + tok] = (float)j1[s][r];
        if (m2[s][r] - m1[s][r] < TAU) {
          int pos = atomicAdd(amb_cnt, 1);
          if (pos < TOKENS) amb_list[pos] = t0 + tok;
        }
      }
  }
}

// ---------------- exact-np rescan of ambiguous tokens ----------------
// Replicates the round-3-validated bitwise formula: ascending-c fmaf chains,
// d = fl(fl(A+B) - 2M), lex-(d,j) min = np first-occurrence.
__global__ void __launch_bounds__(256)
k_rescan(const float* __restrict__ z, const float* __restrict__ emb,
         const float* __restrict__ en, const int* __restrict__ amb_cnt,
         const int* __restrict__ amb_list, float* __restrict__ out_idx) {
#pragma clang fp contract(off)
  __shared__ float zs[ED];
  __shared__ float dred[256];
  __shared__ int jred[256];
  int n = *amb_cnt;
  if (n > TOKENS) n = TOKENS;
  int tid = threadIdx.x;
  for (int it = blockIdx.x; it < n; it += gridDim.x) {
    int t = amb_list[it];
    int b = t >> 15, s = t & 32767;
    zs[tid] = z[(size_t)b * ED * S + (size_t)tid * S + s];
    __syncthreads();
    float A = 0.f;
    for (int c = 0; c < ED; ++c) A = fmaf(zs[c], zs[c], A);
    float best = 3.4e38f;
    int bj = 0;
    for (int k = 0; k < 4; ++k) {
      int j = tid + k * 256;           // ascending j per thread
      const float* e = emb + (size_t)j * ED;
      float M = 0.f;
      for (int c = 0; c < ED; c += 4) {
        float4 q = *(const float4*)(e + c);
        M = fmaf(zs[c], q.x, M);
        M = fmaf(zs[c + 1], q.y, M);
        M = fmaf(zs[c + 2], q.z, M);
        M = fmaf(zs[c + 3], q.w, M);
      }
      float d = (A + en[j]) - 2.f * M;
      if (d < best) { best = d; bj = j; }
    }
    dred[tid] = best; jred[tid] = bj;
    __syncthreads();
    for (int off = 128; off > 0; off >>= 1) {
      if (tid < off) {
        float db = dred[tid + off]; int jb = jred[tid + off];
        if (db < dred[tid] || (db == dred[tid] && jb < jred[tid])) {
          dred[tid] = db; jred[tid] = jb;
        }
      }
      __syncthreads();
    }
    if (tid == 0) out_idx[t] = (float)jred[0];
    __syncthreads();
  }
}

// ---------------- epilogue: z_q gather + loss + sampled ----------------
__global__ void __launch_bounds__(256)
k_epi(const float* __restrict__ z, const float* __restrict__ emb,
      const float* __restrict__ idxf, float* __restrict__ out_zq,
      float* __restrict__ out_samp, float* __restrict__ out_loss) {
  __shared__ float red[256];
  int tid = threadIdx.x;
  int lane = tid & 63;
  int w = tid >> 6;
  int t0 = blockIdx.x * 64;
  int b = t0 >> 15;
  int s0 = t0 & 32767;

  int jm = (int)idxf[t0 + lane];
  if (w == 0) out_samp[jm] = 1.0f;     // idx < 1024 -> always row 0

  const float* zb = z + ((size_t)b * ED * S) + s0;
  float* zqb = out_zq + ((size_t)b * ED * S) + s0;
  const float* erow = emb + (size_t)jm * ED;
  float lacc = 0.f;
  for (int cc = w; cc < ED; cc += 4) {
    float zq = erow[cc];
    float zv = zb[(size_t)cc * S + lane];
    float df = zq - zv;
    lacc = fmaf(df, df, lacc);
    zqb[(size_t)cc * S + lane] = zq;
  }
  red[tid] = lacc;
  __syncthreads();
  for (int off = 128; off > 0; off >>= 1) {
    if (tid < off) red[tid] += red[tid + off];
    __syncthreads();
  }
  if (tid == 0)
    atomicAdd(out_loss, red[0] * (1.2f / 16777216.0f));  // (1+BETA)*mean
}

// ---------------- codebook self-distance: LDS-tiled fp32 GEMM ----------------
// 256 blocks = 16x16 grid of 64x64 tiles; 4x4 register blocking per thread.
__global__ void __launch_bounds__(256)
k_cd(const float* __restrict__ emb, const float* __restrict__ en,
     float* __restrict__ cd) {
  __shared__ float At[64 * 260];
  __shared__ float Bt[64 * 260];
  int bi = blockIdx.x >> 4, bj = blockIdx.x & 15;
  int tid = threadIdx.x;
  const float4* ev = (const float4*)emb;
  for (int idx = tid; idx < 64 * 64; idx += 256) {
    int row = idx >> 6, c4 = idx & 63;
    *(float4*)(&At[row * 260 + c4 * 4]) = ev[(size_t)(bi * 64 + row) * 64 + c4];
    *(float4*)(&Bt[row * 260 + c4 * 4]) = ev[(size_t)(bj * 64 + row) * 64 + c4];
  }
  __syncthreads();
  int ti = tid & 15, tj = tid >> 4;
  float acc[4][4] = {};
  for (int c = 0; c < ED; c += 4) {
    float4 a[4], bq[4];
#pragma unroll
    for (int p = 0; p < 4; ++p) a[p] = *(const float4*)(&At[(ti * 4 + p) * 260 + c]);
#pragma unroll
    for (int q = 0; q < 4; ++q) bq[q] = *(const float4*)(&Bt[(tj * 4 + q) * 260 + c]);
#pragma unroll
    for (int p = 0; p < 4; ++p)
#pragma unroll
      for (int q = 0; q < 4; ++q) {
        acc[p][q] = fmaf(a[p].x, bq[q].x, acc[p][q]);
        acc[p][q] = fmaf(a[p].y, bq[q].y, acc[p][q]);
        acc[p][q] = fmaf(a[p].z, bq[q].z, acc[p][q]);
        acc[p][q] = fmaf(a[p].w, bq[q].w, acc[p][q]);
      }
  }
#pragma unroll
  for (int p = 0; p < 4; ++p)
#pragma unroll
    for (int q = 0; q < 4; ++q) {
      int i = bi * 64 + ti * 4 + p;
      int j = bj * 64 + tj * 4 + q;
      cd[(size_t)i * NE + j] = (en[i] + en[j]) - 2.f * acc[p][q];
    }
}

// ---------------- per-column 2nd smallest -> mean ----------------
__global__ void __launch_bounds__(256)
k_colstats(const float* __restrict__ cd, float* __restrict__ out_md) {
  int tid = threadIdx.x;
  int j = blockIdx.x * 64 + (tid & 63);
  int chunk = tid >> 6;
  float m1 = 3.4e38f, m2 = 3.4e38f;
  int r0 = chunk * 256;
  for (int r = r0; r < r0 + 256; ++r) {
    float v = cd[(size_t)r * NE + j];
    if (v < m1) { m2 = m1; m1 = v; }
    else if (v < m2) { m2 = v; }
  }
  __shared__ float s1[256], s2[256];
  s1[tid] = m1; s2[tid] = m2;
  __syncthreads();
  if (chunk == 0) {
    for (int cc = 1; cc < 4; ++cc) {
      float n1 = s1[tid + cc * 64], n2 = s2[tid + cc * 64];
      float lo = fminf(m1, n1);
      float hi = fmaxf(m1, n1);
      m2 = fminf(hi, fminf(m2, n2));
      m1 = lo;
    }
    atomicAdd(out_md, m2 * (1.0f / 1024.0f));
  }
}

// ---------------- per-row variance (ddof=1) -> mean ----------------
__global__ void k_var(const float* __restrict__ cd, float* __restrict__ out_mv) {
  int i = blockIdx.x;
  int tid = threadIdx.x;
  const float* row = cd + (size_t)i * NE;
  __shared__ float red[256];
  float s = row[tid] + row[tid + 256] + row[tid + 512] + row[tid + 768];
  red[tid] = s;
  __syncthreads();
  for (int off = 128; off > 0; off >>= 1) {
    if (tid < off) red[tid] += red[tid + off];
    __syncthreads();
  }
  float mean = red[0] * (1.0f / 1024.0f);
  __syncthreads();
  float d0 = row[tid] - mean, d1 = row[tid + 256] - mean,
        d2 = row[tid + 512] - mean, d3 = row[tid + 768] - mean;
  red[tid] = d0 * d0 + d1 * d1 + d2 * d2 + d3 * d3;
  __syncthreads();
  for (int off = 128; off > 0; off >>= 1) {
    if (tid < off) red[tid] += red[tid + off];
    __syncthreads();
  }
  if (tid == 0)
    atomicAdd(out_mv, red[0] * (1.0f / 1023.0f) * (1.0f / 1024.0f));
}

extern "C" void kernel_launch(void* const* d_in, const int* in_sizes, int n_in,
                              void* d_out, int out_size, void* d_ws, size_t ws_size,
                              hipStream_t stream) {
  const float* z   = (const float*)d_in[0];
  const float* emb = (const float*)d_in[1];
  float* out = (float*)d_out;

  float* cd = (float*)d_ws;                       // 4 MiB
  float* en = cd + (size_t)NE * NE;               // 4 KiB
  _Float16* embf = (_Float16*)(en + NE);          // 512 KiB fragment-ordered fp16
  int* amb_cnt = (int*)(embf + (size_t)NE * ED);
  int* amb_list = amb_cnt + 16;                   // up to TOKENS ints

  hipMemsetAsync(out + OFF_LOSS, 0,
                 (size_t)(out_size - OFF_LOSS) * sizeof(float), stream);
  hipMemsetAsync(amb_cnt, 0, sizeof(int), stream);

  k_enorm<<<NE / 256, 256, 0, stream>>>(emb, en);
  k_cvt<<<64, 512, 0, stream>>>(emb, embf);
  k_filter<<<TOKENS / 128, 256, 0, stream>>>(z, embf, en, out + OFF_IDX,
                                             amb_cnt, amb_list);
  k_rescan<<<1024, 256, 0, stream>>>(z, emb, en, amb_cnt, amb_list, out + OFF_IDX);
  k_epi<<<TOKENS / 64, 256, 0, stream>>>(z, emb, out + OFF_IDX,
                                         out, out + OFF_SAMP, out + OFF_LOSS);
  k_cd<<<256, 256, 0, stream>>>(emb, en, cd);
  k_colstats<<<16, 256, 0, stream>>>(cd, out + OFF_MD);
  k_var<<<NE, 256, 0, stream>>>(cd, out + OFF_MV);
}

// Round 6
// 519.158 us; speedup vs baseline: 2.8435x; 2.8435x over previous
//
#include <hip/hip_runtime.h>
#include <stdint.h>

#define NE   1024
#define ED   256
#define NB   2
#define S    32768            // 32*32*32
#define TOKENS (NB*S)         // 65536

#define OFF_LOSS 16777216
#define OFF_IDX  16777217
#define OFF_SAMP 16842753
#define OFF_MD   16844801
#define OFF_MV   16844802

#define TAU 2.5e-4f           // fp16-filter ambiguity margin (~6 sigma of 3e-5 err)

typedef _Float16 half8 __attribute__((ext_vector_type(8)));
typedef float floatx4 __attribute__((ext_vector_type(4)));

// ---------------- codebook norms: bitwise numpy pairwise sum ----------------
__global__ void k_enorm(const float* __restrict__ emb, float* __restrict__ en) {
#pragma clang fp contract(off)
  int j = blockIdx.x * 256 + threadIdx.x;
  const float* e = emb + (size_t)j * ED;
  float halves[2];
  for (int h = 0; h < 2; ++h) {
    const float* a = e + h * 128;
    float r[8];
    for (int k = 0; k < 8; ++k) r[k] = a[k] * a[k];
    for (int i = 8; i < 128; i += 8)
      for (int k = 0; k < 8; ++k) r[k] += a[i + k] * a[i + k];
    halves[h] = ((r[0] + r[1]) + (r[2] + r[3])) + ((r[4] + r[5]) + (r[6] + r[7]));
  }
  en[j] = halves[0] + halves[1];
}

// ---------------- emb -> fragment-ordered fp16 ----------------
__global__ void k_cvt(const float* __restrict__ emb, _Float16* __restrict__ embf) {
  int g = blockIdx.x * 512 + threadIdx.x;   // 64 blocks x 512 = 32768
  int lane = g & 63;
  int ks = (g >> 6) & 7;
  int nt = g >> 9;
  int n = nt * 16 + (lane & 15);
  int k0 = ks * 32 + (lane >> 4) * 8;
  const float* src = emb + (size_t)n * ED + k0;
  half8 v;
#pragma unroll
  for (int j = 0; j < 8; ++j) v[j] = (_Float16)src[j];
  *(half8*)(embf + ((size_t)((nt * 8 + ks) * 64 + lane)) * 8) = v;
}

// ---------------- MFMA filter: approx argmin + top-2 ambiguity ----------------
// 128 tokens/block, 256 thr = 4 waves; wave w owns tokens [w*32, w*32+32)
// (2 m-stripes of 16). Sweeps all 1024 codes via 64 n-tiles of 16x16x32 mfma.
__global__ void __launch_bounds__(256)
k_filter(const float* __restrict__ z, const _Float16* __restrict__ embf,
         const float* __restrict__ en, float* __restrict__ out_idx,
         int* __restrict__ amb_cnt, int* __restrict__ amb_list) {
  __shared__ _Float16 zA[128 * 264];   // [tok][c], stride 264 -> 2-way banks
  __shared__ float en_s[NE];

  int tid = threadIdx.x;
  int lane = tid & 63;
  int w = tid >> 6;
  int mrow = lane & 15;
  int quad = lane >> 4;
  int t0 = blockIdx.x * 128;
  int b = t0 >> 15;                    // 32768 % 128 == 0: no straddle
  int s0 = t0 & 32767;

  for (int i = tid; i < NE; i += 256) en_s[i] = en[i];

  {  // stage z tile -> fp16 LDS (coalesced along s, rne convert)
    int tok = tid & 127;
    int ch = tid >> 7;
    const float* zb = z + (size_t)b * ED * S + s0 + tok;
    for (int it = 0; it < 16; ++it) {
      int c0 = ch * 8 + it * 16;
      half8 v;
#pragma unroll
      for (int j = 0; j < 8; ++j) v[j] = (_Float16)zb[(size_t)(c0 + j) * S];
      *(half8*)(&zA[tok * 264 + c0]) = v;
    }
  }
  __syncthreads();

  // A-frags register-resident: af[stripe][kstep]
  half8 af[2][8];
#pragma unroll
  for (int s = 0; s < 2; ++s)
#pragma unroll
    for (int ks = 0; ks < 8; ++ks)
      af[s][ks] = *(const half8*)(&zA[(w * 32 + s * 16 + mrow) * 264 + ks * 32 + quad * 8]);

  float m1[2][4], m2[2][4];
  int j1[2][4];
#pragma unroll
  for (int s = 0; s < 2; ++s)
#pragma unroll
    for (int r = 0; r < 4; ++r) { m1[s][r] = 3.4e38f; m2[s][r] = 3.4e38f; j1[s][r] = 0; }

  for (int nt = 0; nt < 64; ++nt) {
    floatx4 acc0 = {0.f, 0.f, 0.f, 0.f}, acc1 = {0.f, 0.f, 0.f, 0.f};
    const half8* pb = (const half8*)(embf + ((size_t)(nt * 8) * 64 + lane) * 8);
#pragma unroll
    for (int ks = 0; ks < 8; ++ks) {
      half8 bf = pb[ks * 64];          // coalesced 16B/lane from L2
      acc0 = __builtin_amdgcn_mfma_f32_16x16x32_f16(af[0][ks], bf, acc0, 0, 0, 0);
      acc1 = __builtin_amdgcn_mfma_f32_16x16x32_f16(af[1][ks], bf, acc1, 0, 0, 0);
    }
    int j = nt * 16 + mrow;
    float Bj = en_s[j];                // ||z||^2 constant per token -> dropped
#pragma unroll
    for (int r = 0; r < 4; ++r) {
      float d0 = Bj - 2.f * acc0[r];
      float d1 = Bj - 2.f * acc1[r];
      if (d0 < m1[0][r]) { m2[0][r] = m1[0][r]; m1[0][r] = d0; j1[0][r] = j; }
      else if (d0 < m2[0][r]) m2[0][r] = d0;
      if (d1 < m1[1][r]) { m2[1][r] = m1[1][r]; m1[1][r] = d1; j1[1][r] = j; }
      else if (d1 < m2[1][r]) m2[1][r] = d1;
    }
  }

  // merge across the 16 lanes of each quad (same tokens, different codes)
#pragma unroll
  for (int d = 1; d < 16; d <<= 1) {
#pragma unroll
    for (int s = 0; s < 2; ++s)
#pragma unroll
      for (int r = 0; r < 4; ++r) {
        float om1 = __shfl_xor(m1[s][r], d, 64);
        float om2 = __shfl_xor(m2[s][r], d, 64);
        int oj = __shfl_xor(j1[s][r], d, 64);
        float hi;
        if (om1 < m1[s][r] || (om1 == m1[s][r] && oj < j1[s][r])) {
          hi = m1[s][r]; m1[s][r] = om1; j1[s][r] = oj;
        } else hi = om1;                 // equal-m1 merges force m2==m1 -> flagged
        m2[s][r] = fminf(m2[s][r], fminf(om2, hi));
      }
  }

  if (mrow == 0) {
#pragma unroll
    for (int s = 0; s < 2; ++s)
#pragma unroll
      for (int r = 0; r < 4; ++r) {
        int tok = w * 32 + s * 16 + quad * 4 + r;
        out_idx[t0 + tok] = (float)j1[s][r];
        if (m2[s][r] - m1[s][r] < TAU) {
          int pos = atomicAdd(amb_cnt, 1);
          if (pos < TOKENS) amb_list[pos] = t0 + tok;
        }
      }
  }
}

// ---------------- exact-np rescan: 16 tokens/block, tiled ----------------
// thread (tk = tid&15, g = tid>>4): token tk of the tile, codes [g*64,(g+1)*64).
// Bitwise round-3/4 formula: ascending-c fmaf chains, d = fl(fl(A+B) - 2M),
// lex-(d,j) merge in ascending-g (= ascending code) order.
__global__ void __launch_bounds__(256)
k_rescan(const float* __restrict__ z, const float* __restrict__ emb,
         const float* __restrict__ en, const int* __restrict__ amb_cnt,
         const int* __restrict__ amb_list, float* __restrict__ out_idx) {
#pragma clang fp contract(off)
  __shared__ float zs[16][260];
  __shared__ float m1s[16][17];
  __shared__ int   jms[16][17];
  int n = *amb_cnt;
  if (n > TOKENS) n = TOKENS;
  int ntiles = (n + 15) >> 4;
  int tid = threadIdx.x;
  int tk = tid & 15, g = tid >> 4;

  for (int tile = blockIdx.x; tile < ntiles; tile += gridDim.x) {
    __syncthreads();                       // protect zs/m1s reuse across tiles
    int i = tile * 16 + tk;
    int li = i < n ? i : n - 1;
    int t = amb_list[li];
    int b = t >> 15, s = t & 32767;
    const float* zb = z + (size_t)b * ED * S + s;
#pragma unroll
    for (int ii = 0; ii < 16; ++ii) {
      int c = g * 16 + ii;
      zs[tk][c] = zb[(size_t)c * S];
    }
    __syncthreads();

    // A = ||z||^2, ascending float4 chain (round-4-validated order)
    float A = 0.f;
    for (int c = 0; c < ED; c += 4) {
      float4 zv = *(const float4*)(&zs[tk][c]);
      A = fmaf(zv.x, zv.x, A); A = fmaf(zv.y, zv.y, A);
      A = fmaf(zv.z, zv.z, A); A = fmaf(zv.w, zv.w, A);
    }

    float best = 3.4e38f;
    int bj = 0;
    for (int jj = 0; jj < 16; ++jj) {
      int j0 = g * 64 + jj * 4;
      const float* e0 = emb + (size_t)j0 * ED;
      float a0 = 0.f, a1 = 0.f, a2 = 0.f, a3 = 0.f;
      for (int c = 0; c < ED; c += 4) {
        float4 zv = *(const float4*)(&zs[tk][c]);
        float4 q0 = *(const float4*)(e0 + c);
        float4 q1 = *(const float4*)(e0 + 256 + c);
        float4 q2 = *(const float4*)(e0 + 512 + c);
        float4 q3 = *(const float4*)(e0 + 768 + c);
        a0 = fmaf(zv.x, q0.x, a0); a0 = fmaf(zv.y, q0.y, a0);
        a0 = fmaf(zv.z, q0.z, a0); a0 = fmaf(zv.w, q0.w, a0);
        a1 = fmaf(zv.x, q1.x, a1); a1 = fmaf(zv.y, q1.y, a1);
        a1 = fmaf(zv.z, q1.z, a1); a1 = fmaf(zv.w, q1.w, a1);
        a2 = fmaf(zv.x, q2.x, a2); a2 = fmaf(zv.y, q2.y, a2);
        a2 = fmaf(zv.z, q2.z, a2); a2 = fmaf(zv.w, q2.w, a2);
        a3 = fmaf(zv.x, q3.x, a3); a3 = fmaf(zv.y, q3.y, a3);
        a3 = fmaf(zv.z, q3.z, a3); a3 = fmaf(zv.w, q3.w, a3);
      }
      float d0 = (A + en[j0 + 0]) - 2.f * a0;
      float d1 = (A + en[j0 + 1]) - 2.f * a1;
      float d2 = (A + en[j0 + 2]) - 2.f * a2;
      float d3 = (A + en[j0 + 3]) - 2.f * a3;
      if (d0 < best) { best = d0; bj = j0 + 0; }
      if (d1 < best) { best = d1; bj = j0 + 1; }
      if (d2 < best) { best = d2; bj = j0 + 2; }
      if (d3 < best) { best = d3; bj = j0 + 3; }
    }
    m1s[tk][g] = best;
    jms[tk][g] = bj;
    __syncthreads();

    if (tid < 16 && tile * 16 + tid < n) {
      float gm = m1s[tid][0];
      int gj = jms[tid][0];
      for (int gg = 1; gg < 16; ++gg) {    // ascending code ranges: first-idx
        float dv = m1s[tid][gg];
        int jv = jms[tid][gg];
        if (dv < gm) { gm = dv; gj = jv; }
      }
      out_idx[amb_list[tile * 16 + tid]] = (float)gj;
    }
  }
}

// ---------------- epilogue: z_q gather + loss + sampled ----------------
__global__ void __launch_bounds__(256)
k_epi(const float* __restrict__ z, const float* __restrict__ emb,
      const float* __restrict__ idxf, float* __restrict__ out_zq,
      float* __restrict__ out_samp, float* __restrict__ out_loss) {
  __shared__ float red[256];
  int tid = threadIdx.x;
  int lane = tid & 63;
  int w = tid >> 6;
  int t0 = blockIdx.x * 64;
  int b = t0 >> 15;
  int s0 = t0 & 32767;

  int jm = (int)idxf[t0 + lane];
  if (w == 0) out_samp[jm] = 1.0f;     // idx < 1024 -> always row 0

  const float* zb = z + ((size_t)b * ED * S) + s0;
  float* zqb = out_zq + ((size_t)b * ED * S) + s0;
  const float* erow = emb + (size_t)jm * ED;
  float lacc = 0.f;
  for (int cc = w; cc < ED; cc += 4) {
    float zq = erow[cc];
    float zv = zb[(size_t)cc * S + lane];
    float df = zq - zv;
    lacc = fmaf(df, df, lacc);
    zqb[(size_t)cc * S + lane] = zq;
  }
  red[tid] = lacc;
  __syncthreads();
  for (int off = 128; off > 0; off >>= 1) {
    if (tid < off) red[tid] += red[tid + off];
    __syncthreads();
  }
  if (tid == 0)
    atomicAdd(out_loss, red[0] * (1.2f / 16777216.0f));  // (1+BETA)*mean
}

// ---------------- codebook self-distance: LDS-tiled fp32 GEMM ----------------
__global__ void __launch_bounds__(256)
k_cd(const float* __restrict__ emb, const float* __restrict__ en,
     float* __restrict__ cd) {
  __shared__ float At[64 * 260];
  __shared__ float Bt[64 * 260];
  int bi = blockIdx.x >> 4, bj = blockIdx.x & 15;
  int tid = threadIdx.x;
  const float4* ev = (const float4*)emb;
  for (int idx = tid; idx < 64 * 64; idx += 256) {
    int row = idx >> 6, c4 = idx & 63;
    *(float4*)(&At[row * 260 + c4 * 4]) = ev[(size_t)(bi * 64 + row) * 64 + c4];
    *(float4*)(&Bt[row * 260 + c4 * 4]) = ev[(size_t)(bj * 64 + row) * 64 + c4];
  }
  __syncthreads();
  int ti = tid & 15, tj = tid >> 4;
  float acc[4][4] = {};
  for (int c = 0; c < ED; c += 4) {
    float4 a[4], bq[4];
#pragma unroll
    for (int p = 0; p < 4; ++p) a[p] = *(const float4*)(&At[(ti * 4 + p) * 260 + c]);
#pragma unroll
    for (int q = 0; q < 4; ++q) bq[q] = *(const float4*)(&Bt[(tj * 4 + q) * 260 + c]);
#pragma unroll
    for (int p = 0; p < 4; ++p)
#pragma unroll
      for (int q = 0; q < 4; ++q) {
        acc[p][q] = fmaf(a[p].x, bq[q].x, acc[p][q]);
        acc[p][q] = fmaf(a[p].y, bq[q].y, acc[p][q]);
        acc[p][q] = fmaf(a[p].z, bq[q].z, acc[p][q]);
        acc[p][q] = fmaf(a[p].w, bq[q].w, acc[p][q]);
      }
  }
#pragma unroll
  for (int p = 0; p < 4; ++p)
#pragma unroll
    for (int q = 0; q < 4; ++q) {
      int i = bi * 64 + ti * 4 + p;
      int j = bj * 64 + tj * 4 + q;
      cd[(size_t)i * NE + j] = (en[i] + en[j]) - 2.f * acc[p][q];
    }
}

// ---------------- per-column 2nd smallest -> mean ----------------
// 64 blocks x 16 cols; 16 row-chunks of 64 per column, LDS merge.
__global__ void __launch_bounds__(256)
k_colstats(const float* __restrict__ cd, float* __restrict__ out_md) {
  int tid = threadIdx.x;
  int j = blockIdx.x * 16 + (tid & 15);
  int chunk = tid >> 4;
  float m1 = 3.4e38f, m2 = 3.4e38f;
  int r0 = chunk * 64;
  for (int r = r0; r < r0 + 64; ++r) {
    float v = cd[(size_t)r * NE + j];
    if (v < m1) { m2 = m1; m1 = v; }
    else if (v < m2) { m2 = v; }
  }
  __shared__ float s1[256], s2[256];
  s1[tid] = m1; s2[tid] = m2;
  __syncthreads();
  if (chunk == 0) {
    for (int cc = 1; cc < 16; ++cc) {
      float n1 = s1[cc * 16 + tid], n2 = s2[cc * 16 + tid];
      float lo = fminf(m1, n1);
      float hi = fmaxf(m1, n1);
      m2 = fminf(hi, fminf(m2, n2));
      m1 = lo;
    }
    atomicAdd(out_md, m2 * (1.0f / 1024.0f));
  }
}

// ---------------- per-row variance (ddof=1) -> mean ----------------
__global__ void k_var(const float* __restrict__ cd, float* __restrict__ out_mv) {
  int i = blockIdx.x;
  int tid = threadIdx.x;
  const float* row = cd + (size_t)i * NE;
  __shared__ float red[256];
  float s = row[tid] + row[tid + 256] + row[tid + 512] + row[tid + 768];
  red[tid] = s;
  __syncthreads();
  for (int off = 128; off > 0; off >>= 1) {
    if (tid < off) red[tid] += red[tid + off];
    __syncthreads();
  }
  float mean = red[0] * (1.0f / 1024.0f);
  __syncthreads();
  float d0 = row[tid] - mean, d1 = row[tid + 256] - mean,
        d2 = row[tid + 512] - mean, d3 = row[tid + 768] - mean;
  red[tid] = d0 * d0 + d1 * d1 + d2 * d2 + d3 * d3;
  __syncthreads();
  for (int off = 128; off > 0; off >>= 1) {
    if (tid < off) red[tid] += red[tid + off];
    __syncthreads();
  }
  if (tid == 0)
    atomicAdd(out_mv, red[0] * (1.0f / 1023.0f) * (1.0f / 1024.0f));
}

extern "C" void kernel_launch(void* const* d_in, const int* in_sizes, int n_in,
                              void* d_out, int out_size, void* d_ws, size_t ws_size,
                              hipStream_t stream) {
  const float* z   = (const float*)d_in[0];
  const float* emb = (const float*)d_in[1];
  float* out = (float*)d_out;

  float* cd = (float*)d_ws;                       // 4 MiB
  float* en = cd + (size_t)NE * NE;               // 4 KiB
  _Float16* embf = (_Float16*)(en + NE);          // 512 KiB fragment-ordered fp16
  int* amb_cnt = (int*)(embf + (size_t)NE * ED);
  int* amb_list = amb_cnt + 16;                   // up to TOKENS ints

  hipMemsetAsync(out + OFF_LOSS, 0,
                 (size_t)(out_size - OFF_LOSS) * sizeof(float), stream);
  hipMemsetAsync(amb_cnt, 0, sizeof(int), stream);

  k_enorm<<<NE / 256, 256, 0, stream>>>(emb, en);
  k_cvt<<<64, 512, 0, stream>>>(emb, embf);
  k_filter<<<TOKENS / 128, 256, 0, stream>>>(z, embf, en, out + OFF_IDX,
                                             amb_cnt, amb_list);
  k_rescan<<<1024, 256, 0, stream>>>(z, emb, en, amb_cnt, amb_list, out + OFF_IDX);
  k_epi<<<TOKENS / 64, 256, 0, stream>>>(z, emb, out + OFF_IDX,
                                         out, out + OFF_SAMP, out + OFF_LOSS);
  k_cd<<<256, 256, 0, stream>>>(emb, en, cd);
  k_colstats<<<64, 256, 0, stream>>>(cd, out + OFF_MD);
  k_var<<<NE, 256, 0, stream>>>(cd, out + OFF_MV);
}